// Round 1
// 1102.010 us; speedup vs baseline: 1.7100x; 1.7100x over previous
//
#include <hip/hip_runtime.h>
#include <stdint.h>

typedef unsigned short ushort_t;
typedef __attribute__((ext_vector_type(8))) __bf16 bf16x8;
typedef __attribute__((ext_vector_type(4))) float f32x4;

#define BM 128
#define BN 128
#define BK 32

#define M_TOTAL   51200
#define MTILES    400      // 51200 / 128
#define K1        2104
#define K1P       2112     // K padded to mult of 32
#define N1P       2176     // N1 padded to 17*128
#define N2        1024
#define SHIST     50
#define NGRP      1024     // 51200 / 50
#define GMAX      16       // max history-groups tracked in LDS per 128-row tile

__device__ __forceinline__ ushort_t f2bf(float f) {
  union { float f; unsigned u; } v; v.f = f;
  unsigned r = v.u + 0x7FFF + ((v.u >> 16) & 1);
  return (ushort_t)(r >> 16);
}

__device__ __forceinline__ bf16x8 cvt8(f32x4 a0, f32x4 a1) {
  bf16x8 v;
  v[0] = (__bf16)a0[0]; v[1] = (__bf16)a0[1];
  v[2] = (__bf16)a0[2]; v[3] = (__bf16)a0[3];
  v[4] = (__bf16)a1[0]; v[5] = (__bf16)a1[1];
  v[6] = (__bf16)a1[2]; v[7] = (__bf16)a1[3];
  return v;
}

__device__ __forceinline__ void async_cp16(const void* g, void* l) {
  __builtin_amdgcn_global_load_lds(
      (const __attribute__((address_space(1))) void*)g,
      (__attribute__((address_space(3))) void*)l,
      16, 0, 0);
}

// ---------------- weight packs (unchanged) ----------------
// W1 f32 [2104][2104] (k,n) -> W1T bf16 [2176][2112] (n,k), zero padded
__global__ void pack_w1t(const float* __restrict__ w1, ushort_t* __restrict__ w1t) {
  int k = blockIdx.x * 256 + threadIdx.x;
  int n = blockIdx.y;
  if (k >= K1P) return;
  ushort_t v = 0;
  if (k < K1 && n < K1) v = f2bf(w1[(long)k * K1 + n]);
  w1t[(long)n * K1P + k] = v;
}

// W2 f32 [2104][1024] -> W2T bf16 [1024][2112]
__global__ void pack_w2t(const float* __restrict__ w2, ushort_t* __restrict__ w2t) {
  int k = blockIdx.x * 256 + threadIdx.x;
  int n = blockIdx.y;
  if (k >= K1P) return;
  ushort_t v = 0;
  if (k < K1) v = f2bf(w2[(long)k * N2 + n]);
  w2t[(long)n * K1P + k] = v;
}

// ---------------- mask compaction ----------------
// per-group unmasked counts -> cnt[g] (stored into offs buffer)
__global__ void grp_count(const int* __restrict__ mask, int* __restrict__ cnt) {
  int g = blockIdx.x * 256 + threadIdx.x;
  if (g >= NGRP) return;
  const int* mp = mask + (long)g * SHIST;
  int c = 0;
#pragma unroll
  for (int s = 0; s < SHIST; ++s) c += (mp[s] != 0);
  cnt[g] = c;
}

// exclusive scan of 1024 counts; also float counts + header {total, padded}
__global__ void grp_scan(int* __restrict__ offs, float* __restrict__ cntf,
                         int* __restrict__ hdr) {
  __shared__ int sc[NGRP];
  const int t = threadIdx.x;
  const int c = offs[t];
  cntf[t] = (float)c;
  sc[t] = c;
  __syncthreads();
  for (int d = 1; d < NGRP; d <<= 1) {
    int add = (t >= d) ? sc[t - d] : 0;
    __syncthreads();
    sc[t] += add;
    __syncthreads();
  }
  offs[t] = sc[t] - c;                       // exclusive prefix
  if (t == NGRP - 1) {
    hdr[0] = sc[t];                          // total unmasked rows
    hdr[1] = (sc[t] + BM - 1) & ~(BM - 1);   // padded to 128
  }
}

// rowgrp[pos] = -1 for pos >= total (pad rows)
__global__ void pad_fill(const int* __restrict__ hdr, int* __restrict__ rowgrp) {
  int pos = blockIdx.x * 256 + threadIdx.x;
  if (pos < M_TOTAL && pos >= hdr[0]) rowgrp[pos] = -1;
}

// stable compaction: rowmap[pos]=global row, rowgrp[pos]=group (one wave per group)
__global__ void build_map(const int* __restrict__ mask, const int* __restrict__ offs,
                          int* __restrict__ rowmap, int* __restrict__ rowgrp) {
  const int g = blockIdx.x;
  const int lane = threadIdx.x;   // 64
  int ok = (lane < SHIST) ? (mask[(long)g * SHIST + lane] != 0) : 0;
  unsigned long long bal = __ballot(ok);
  if (ok) {
    int rank = __popcll(bal & ((1ull << lane) - 1ull));
    int pos = offs[g] + rank;
    rowmap[pos] = g * SHIST + lane;
    rowgrp[pos] = g;
  }
}

// gather+convert compacted rows into X bf16 [padded][2112]; one block per row
__global__ __launch_bounds__(256)
void pack_x(const float* __restrict__ emb, const float* __restrict__ vis,
            const float* __restrict__ bbox, const float* __restrict__ kp,
            const int* __restrict__ hdr, const int* __restrict__ rowmap,
            const int* __restrict__ rowgrp, ushort_t* __restrict__ X) {
  const int pos = blockIdx.x;
  if (pos >= hdr[1]) return;
  const int t = threadIdx.x;
  ushort_t* xr = X + (long)pos * K1P;
  const int g = rowgrp[pos];
  if (g < 0) {                               // pad row: zero it
    f32x4 z = {0.f, 0.f, 0.f, 0.f};
    for (int c = t; c < K1P / 8; c += 256) *(f32x4*)&xr[c * 8] = z;
    return;
  }
  const long r = rowmap[pos];
  {
    const float* src = emb + r * 2048 + t * 8;
    f32x4 a0 = *(const f32x4*)src;
    f32x4 a1 = *(const f32x4*)(src + 4);
    *(bf16x8*)&xr[t * 8] = cvt8(a0, a1);
  }
  if (t < 64) {                              // cols 2048..2111
    float v = 0.f;
    if (t == 0)       v = vis[r];
    else if (t < 5)   v = bbox[r * 4 + (t - 1)];
    else if (t < 56)  v = kp[r * 51 + (t - 5)];
    xr[2048 + t] = f2bf(v);
  }
}

__global__ void zero_g(float* __restrict__ G) {
  G[blockIdx.x * 256 + threadIdx.x] = 0.f;
}

// ---------------- GEMM1 fused: G[g][n] += relu(X @ W1 + b1) ----------------
__global__ __launch_bounds__(256)
void gemm1(const ushort_t* __restrict__ X, const ushort_t* __restrict__ w1t,
           const float* __restrict__ b1, const int* __restrict__ hdr,
           const int* __restrict__ rowgrp, float* __restrict__ G) {
  const int m0 = blockIdx.y * BM;
  if (m0 >= hdr[1]) return;                  // beyond padded row count
  __shared__ __align__(16) ushort_t la[BM * BK];
  __shared__ __align__(16) ushort_t lb[BN * BK];
  __shared__ float sgrp[GMAX * BN];
  __shared__ int srg[BM];
  const int tid  = threadIdx.x;
  const int lane = tid & 63;
  const int l15  = lane & 15;
  const int quad = lane >> 4;
  const int wave = tid >> 6;
  const int wm   = (wave & 1) * 64;
  const int wn   = (wave >> 1) * 64;
  const int n0   = blockIdx.x * BN;          // [0,2176)

  if (tid < BM) srg[tid] = rowgrp[m0 + tid]; // non-decreasing; -1 = pad
  for (int z = tid; z < GMAX * BN; z += 256) sgrp[z] = 0.f;

  f32x4 acc[4][4];
#pragma unroll
  for (int i = 0; i < 4; ++i)
#pragma unroll
    for (int j = 0; j < 4; ++j) {
      f32x4 z = {0.f, 0.f, 0.f, 0.f};
      acc[i][j] = z;
    }

  for (int ks = 0; ks < K1P / BK; ++ks) {
    const int k0 = ks * BK;
#pragma unroll
    for (int p = 0; p < 2; ++p) {
      int ci  = p * 256 + tid;
      int row = ci >> 2;
      int kc  = (ci & 3) * 8;
      async_cp16(&X[(long)(m0 + row) * K1P + k0 + kc], &la[ci * 8]);
    }
#pragma unroll
    for (int p = 0; p < 2; ++p) {
      int ci  = p * 256 + tid;
      int row = ci >> 2;
      int kc  = (ci & 3) * 8;
      async_cp16(&w1t[(long)(n0 + row) * K1P + k0 + kc], &lb[ci * 8]);
    }
    __syncthreads();
    bf16x8 af[4], bfr[4];
#pragma unroll
    for (int i = 0; i < 4; ++i)
      af[i] = *(const bf16x8*)&la[(wm + i * 16 + l15) * BK + quad * 8];
#pragma unroll
    for (int j = 0; j < 4; ++j)
      bfr[j] = *(const bf16x8*)&lb[(wn + j * 16 + l15) * BK + quad * 8];
#pragma unroll
    for (int i = 0; i < 4; ++i)
#pragma unroll
      for (int j = 0; j < 4; ++j)
        acc[i][j] = __builtin_amdgcn_mfma_f32_16x16x32_bf16(af[i], bfr[j], acc[i][j], 0, 0, 0);
    __syncthreads();
  }

  // epilogue: bias + relu, group-reduce into sgrp (fallback: direct atomic)
  const int gf = srg[0];                     // first (=min) group in tile, >=0
#pragma unroll
  for (int i = 0; i < 4; ++i) {
    const int mb = wm + i * 16 + quad * 4;   // block-local row of reg r=0
#pragma unroll
    for (int j = 0; j < 4; ++j) {
      const int cl = wn + j * 16 + l15;
      const int n  = n0 + cl;
      if (n < K1P) {
        const float bv = (n < K1) ? b1[n] : 0.f;
        float s = 0.f;
        int gp = srg[mb];
#pragma unroll
        for (int r = 0; r < 4; ++r) {
          int g = srg[mb + r];
          if (g != gp) {
            if (gp >= 0 && s != 0.f) {
              int gi = gp - gf;
              if (gi < GMAX) atomicAdd(&sgrp[gi * BN + cl], s);
              else           atomicAdd(&G[(long)gp * K1P + n], s);
            }
            s = 0.f; gp = g;
          }
          if (g >= 0) s += fmaxf(acc[i][j][r] + bv, 0.f);
        }
        if (gp >= 0 && s != 0.f) {
          int gi = gp - gf;
          if (gi < GMAX) atomicAdd(&sgrp[gi * BN + cl], s);
          else           atomicAdd(&G[(long)gp * K1P + n], s);
        }
      }
    }
  }
  __syncthreads();
  for (int z = tid; z < GMAX * BN; z += 256) {
    float v = sgrp[z];
    if (v != 0.f) {
      int gi = z >> 7, cl = z & 127;
      int n = n0 + cl;
      int g = gf + gi;
      if (n < K1P && g < NGRP) atomicAdd(&G[(long)g * K1P + n], v);
    }
  }
}

// ---------------- GEMM2 (tiny): out = (G @ W2 + cnt*b2) / 50 ----------------
// A = G f32, split hi/lo bf16 in staging for ~f32 precision (2 MFMA per frag).
__global__ __launch_bounds__(256)
void gemm2(const float* __restrict__ G, const ushort_t* __restrict__ w2t,
           const float* __restrict__ b2, const float* __restrict__ cntf,
           float* __restrict__ out) {
  __shared__ __align__(16) ushort_t lah[BM * BK];
  __shared__ __align__(16) ushort_t lal[BM * BK];
  __shared__ __align__(16) ushort_t lb[BN * BK];
  const int tid  = threadIdx.x;
  const int lane = tid & 63;
  const int l15  = lane & 15;
  const int quad = lane >> 4;
  const int wave = tid >> 6;
  const int wm   = (wave & 1) * 64;
  const int wn   = (wave >> 1) * 64;
  const int m0   = blockIdx.y * BM;          // group rows [0,1024)
  const int n0   = blockIdx.x * BN;          // [0,1024)

  f32x4 acc[4][4];
#pragma unroll
  for (int i = 0; i < 4; ++i)
#pragma unroll
    for (int j = 0; j < 4; ++j) {
      f32x4 z = {0.f, 0.f, 0.f, 0.f};
      acc[i][j] = z;
    }

  for (int ks = 0; ks < K1P / BK; ++ks) {
    const int k0 = ks * BK;
#pragma unroll
    for (int p = 0; p < 2; ++p) {
      int ci  = p * 256 + tid;
      int row = ci >> 2;
      int kc  = (ci & 3) * 8;
      async_cp16(&w2t[(long)(n0 + row) * K1P + k0 + kc], &lb[ci * 8]);
    }
#pragma unroll
    for (int p = 0; p < 2; ++p) {
      int ci  = p * 256 + tid;
      int row = ci >> 2;
      int kc  = (ci & 3) * 8;
      const float* src = &G[(long)(m0 + row) * K1P + k0 + kc];
      f32x4 a0 = *(const f32x4*)src;
      f32x4 a1 = *(const f32x4*)(src + 4);
      bf16x8 hi = cvt8(a0, a1);
      f32x4 r0, r1;
#pragma unroll
      for (int e = 0; e < 4; ++e) {
        r0[e] = a0[e] - (float)hi[e];
        r1[e] = a1[e] - (float)hi[e + 4];
      }
      bf16x8 lo = cvt8(r0, r1);
      *(bf16x8*)&lah[ci * 8] = hi;
      *(bf16x8*)&lal[ci * 8] = lo;
    }
    __syncthreads();
    bf16x8 ah[4], al[4], bfr[4];
#pragma unroll
    for (int i = 0; i < 4; ++i) {
      ah[i] = *(const bf16x8*)&lah[(wm + i * 16 + l15) * BK + quad * 8];
      al[i] = *(const bf16x8*)&lal[(wm + i * 16 + l15) * BK + quad * 8];
    }
#pragma unroll
    for (int j = 0; j < 4; ++j)
      bfr[j] = *(const bf16x8*)&lb[(wn + j * 16 + l15) * BK + quad * 8];
#pragma unroll
    for (int i = 0; i < 4; ++i)
#pragma unroll
      for (int j = 0; j < 4; ++j) {
        acc[i][j] = __builtin_amdgcn_mfma_f32_16x16x32_bf16(ah[i], bfr[j], acc[i][j], 0, 0, 0);
        acc[i][j] = __builtin_amdgcn_mfma_f32_16x16x32_bf16(al[i], bfr[j], acc[i][j], 0, 0, 0);
      }
    __syncthreads();
  }

  // epilogue: + cnt[g]*b2, /50, direct store (no atomics)
#pragma unroll
  for (int i = 0; i < 4; ++i) {
    int gb = m0 + wm + i * 16 + quad * 4;
#pragma unroll
    for (int j = 0; j < 4; ++j) {
      int n = n0 + wn + j * 16 + l15;
      float bv = b2[n];
#pragma unroll
      for (int r = 0; r < 4; ++r) {
        int g = gb + r;
        out[(long)g * N2 + n] = (acc[i][j][r] + cntf[g] * bv) * (1.0f / 50.0f);
      }
    }
  }
}

extern "C" void kernel_launch(void* const* d_in, const int* in_sizes, int n_in,
                              void* d_out, int out_size, void* d_ws, size_t ws_size,
                              hipStream_t stream) {
  const float* emb  = (const float*)d_in[0];
  const float* vis  = (const float*)d_in[1];
  const float* bbox = (const float*)d_in[2];
  const float* kp   = (const float*)d_in[3];
  const int*   mask = (const int*)d_in[4];
  const float* w1   = (const float*)d_in[5];
  const float* b1   = (const float*)d_in[6];
  const float* w2   = (const float*)d_in[7];
  const float* b2   = (const float*)d_in[8];
  float* out = (float*)d_out;

  // ws layout (bytes), all 16B aligned; total = 238,854,160
  char* ws = (char*)d_ws;
  ushort_t* w1t    = (ushort_t*)(ws);               //  9,191,424 (2176*2112*2)
  ushort_t* w2t    = (ushort_t*)(ws +  9191424);    //  4,325,376 (1024*2112*2)
  float*    G      = (float*)   (ws + 13516800);    //  8,650,752 (1024*2112*4)
  float*    cntf   = (float*)   (ws + 22167552);    //      4,096
  int*      offs   = (int*)     (ws + 22171648);    //      4,096
  int*      hdr    = (int*)     (ws + 22175744);    //         16
  int*      rowmap = (int*)     (ws + 22175760);    //    204,800
  int*      rowgrp = (int*)     (ws + 22380560);    //    204,800
  ushort_t* X      = (ushort_t*)(ws + 22585360);    // 216,268,800 (51200*2112*2)

  pack_w1t<<<dim3(9, N1P), 256, 0, stream>>>(w1, w1t);
  pack_w2t<<<dim3(9, N2), 256, 0, stream>>>(w2, w2t);

  grp_count<<<dim3(NGRP / 256), 256, 0, stream>>>(mask, offs);
  grp_scan<<<dim3(1), NGRP, 0, stream>>>(offs, cntf, hdr);
  pad_fill<<<dim3(M_TOTAL / 256), 256, 0, stream>>>(hdr, rowgrp);
  build_map<<<dim3(NGRP), 64, 0, stream>>>(mask, offs, rowmap, rowgrp);
  pack_x<<<dim3(M_TOTAL), 256, 0, stream>>>(emb, vis, bbox, kp, hdr, rowmap, rowgrp, X);
  zero_g<<<dim3(NGRP * K1P / 256), 256, 0, stream>>>(G);

  gemm1<<<dim3(N1P / BN, MTILES), 256, 0, stream>>>(X, w1t, b1, hdr, rowgrp, G);
  gemm2<<<dim3(N2 / BN, NGRP / BM), 256, 0, stream>>>(G, w2t, b2, cntf, out);
}